// Round 1
// baseline (947.912 us; speedup 1.0000x reference)
//
#include <hip/hip_runtime.h>
#include <hip/hip_bf16.h>
#include <math.h>

// ---------------------------------------------------------------------------
// GINE model: 3x (GINEConv + BN + ReLU) -> global mean pool -> MLP -> sigmoid
// All f32 baseline. Scatter-add via atomics; GEMMs via LDS-staged row tiles.
// ---------------------------------------------------------------------------

__global__ void k_copy(const float* __restrict__ src, float* __restrict__ dst, int n4) {
    int i = blockIdx.x * blockDim.x + threadIdx.x;
    int st = gridDim.x * blockDim.x;
    const float4* s4 = (const float4*)src;
    float4* d4 = (float4*)dst;
    for (; i < n4; i += st) d4[i] = s4[i];
}

__global__ void k_zero(float* __restrict__ dst, int n4) {
    int i = blockIdx.x * blockDim.x + threadIdx.x;
    int st = gridDim.x * blockDim.x;
    float4* d4 = (float4*)dst;
    float4 z = make_float4(0.f, 0.f, 0.f, 0.f);
    for (; i < n4; i += st) d4[i] = z;
}

// transpose W[J][K] -> Wt[K][J]
__global__ void k_transpose(const float* __restrict__ W, float* __restrict__ Wt, int J, int K) {
    int idx = blockIdx.x * blockDim.x + threadIdx.x;
    if (idx < J * K) {
        int j = idx / K, k = idx % K;
        Wt[k * J + j] = W[idx];
    }
}

// Layer 1 edge kernel: d=64. One wave per edge slot; lane owns channel `lane`.
// m = relu(x[src] + ea @ we.T + be); atomicAdd into aggr[dst].
__global__ __launch_bounds__(256) void k_edge64(
    const float* __restrict__ ea, const int* __restrict__ ei, int E,
    const float* __restrict__ x, const float* __restrict__ we,
    const float* __restrict__ be, float* __restrict__ aggr)
{
    const int lane = threadIdx.x & 63;
    int wid = (blockIdx.x * blockDim.x + threadIdx.x) >> 6;
    int nw  = (gridDim.x * blockDim.x) >> 6;

    float w[32];
    const float4* wrow = (const float4*)(we + lane * 32);
#pragma unroll
    for (int q = 0; q < 8; ++q) {
        float4 t = wrow[q];
        w[4*q] = t.x; w[4*q+1] = t.y; w[4*q+2] = t.z; w[4*q+3] = t.w;
    }
    const float bias = be[lane];

    for (int e = wid; e < E; e += nw) {
        int eu = __builtin_amdgcn_readfirstlane(e);
        int s = ei[eu];
        int d = ei[E + eu];
        const float4* ea4 = (const float4*)(ea + (size_t)eu * 32);
        float acc = bias;
#pragma unroll
        for (int q = 0; q < 8; ++q) {
            float4 t = ea4[q];
            acc += t.x * w[4*q] + t.y * w[4*q+1] + t.z * w[4*q+2] + t.w * w[4*q+3];
        }
        float m = x[(size_t)s * 64 + lane] + acc;
        m = fmaxf(m, 0.0f);
        atomicAdd(&aggr[(size_t)d * 64 + lane], m);
    }
}

// Layers 2/3 edge kernel: d=256. Half-block (128 threads) per edge slot;
// thread owns channels j and j+128 (64 weight VGPRs).
__global__ __launch_bounds__(256) void k_edge256(
    const float* __restrict__ ea, const int* __restrict__ ei, int E,
    const float* __restrict__ h, const float* __restrict__ we,
    const float* __restrict__ be, float* __restrict__ aggr)
{
    const int j   = threadIdx.x & 127;
    const int sub = threadIdx.x >> 7;   // 0 or 1
    int slot  = blockIdx.x * 2 + sub;
    int nslot = gridDim.x * 2;

    float wa[32], wb[32];
    const float4* ra = (const float4*)(we + j * 32);
    const float4* rb = (const float4*)(we + (j + 128) * 32);
#pragma unroll
    for (int q = 0; q < 8; ++q) {
        float4 t = ra[q];
        wa[4*q] = t.x; wa[4*q+1] = t.y; wa[4*q+2] = t.z; wa[4*q+3] = t.w;
        float4 u = rb[q];
        wb[4*q] = u.x; wb[4*q+1] = u.y; wb[4*q+2] = u.z; wb[4*q+3] = u.w;
    }
    const float ba = be[j], bb = be[j + 128];

    for (int e = slot; e < E; e += nslot) {
        int eu = __builtin_amdgcn_readfirstlane(e);
        int s = ei[eu];
        int d = ei[E + eu];
        const float4* ea4 = (const float4*)(ea + (size_t)eu * 32);
        float acca = ba, accb = bb;
#pragma unroll
        for (int q = 0; q < 8; ++q) {
            float4 t = ea4[q];
            acca += t.x * wa[4*q] + t.y * wa[4*q+1] + t.z * wa[4*q+2] + t.w * wa[4*q+3];
            accb += t.x * wb[4*q] + t.y * wb[4*q+1] + t.z * wb[4*q+2] + t.w * wb[4*q+3];
        }
        float ma = fmaxf(h[(size_t)s * 256 + j] + acca, 0.0f);
        float mb = fmaxf(h[(size_t)s * 256 + j + 128] + accb, 0.0f);
        atomicAdd(&aggr[(size_t)d * 256 + j], ma);
        atomicAdd(&aggr[(size_t)d * 256 + j + 128], mb);
    }
}

// Node GEMM + BN + ReLU: out[N,256] = relu(BN(A[N,K] @ Wt[K,256] + bnb))
// Block: 256 threads, 32 rows staged in LDS; thread owns output column tid.
template<int K>
__global__ __launch_bounds__(256) void k_node(
    const float* __restrict__ A, const float* __restrict__ Wt,
    const float* __restrict__ bnb, const float* __restrict__ g,
    const float* __restrict__ b, const float* __restrict__ rm,
    const float* __restrict__ rv, float* __restrict__ out, int N)
{
    __shared__ float As[32 * K];
    const int tid = threadIdx.x;
    const int row0 = blockIdx.x * 32;
    const int nrows = min(32, N - row0);

    if (nrows == 32) {
        const float4* Ag = (const float4*)(A + (size_t)row0 * K);
        float4* As4 = (float4*)As;
        for (int i = tid; i < 32 * K / 4; i += 256) As4[i] = Ag[i];
    } else {
        for (int i = tid; i < nrows * K; i += 256) As[i] = A[(size_t)row0 * K + i];
    }
    __syncthreads();

    float acc[32];
#pragma unroll
    for (int i = 0; i < 32; ++i) acc[i] = 0.0f;

    for (int k = 0; k < K; ++k) {
        float w = Wt[k * 256 + tid];
#pragma unroll
        for (int i = 0; i < 32; ++i) acc[i] += As[i * K + k] * w;
    }

    const float bias = bnb[tid];
    const float scale = g[tid] * rsqrtf(rv[tid] + 1e-5f);
    const float shift = b[tid] - rm[tid] * scale;
#pragma unroll
    for (int i = 0; i < 32; ++i) {
        if (i < nrows) {
            float v = (acc[i] + bias) * scale + shift;
            out[(size_t)(row0 + i) * 256 + tid] = fmaxf(v, 0.0f);
        }
    }
}

// Global mean pool (sum + count) via atomics. One wave per node.
__global__ __launch_bounds__(256) void k_pool(
    const float* __restrict__ h, const int* __restrict__ batch, int N,
    float* __restrict__ sums, float* __restrict__ cnt)
{
    const int lane = threadIdx.x & 63;
    int wid = (blockIdx.x * blockDim.x + threadIdx.x) >> 6;
    int nw  = (gridDim.x * blockDim.x) >> 6;
    for (int i = wid; i < N; i += nw) {
        int gi = batch[i];
#pragma unroll
        for (int c = 0; c < 4; ++c) {
            atomicAdd(&sums[(size_t)gi * 256 + c * 64 + lane],
                      h[(size_t)i * 256 + c * 64 + lane]);
        }
        if (lane == 0) atomicAdd(&cnt[gi], 1.0f);
    }
}

// Head: pooled = sums/max(cnt,1); z = relu(pooled@w4t + b4); out = sigmoid(z.w5 + b5)
__global__ __launch_bounds__(128) void k_head(
    const float* __restrict__ sums, const float* __restrict__ cnt,
    const float* __restrict__ w4t, const float* __restrict__ b4,
    const float* __restrict__ w5, const float* __restrict__ b5,
    float* __restrict__ out)
{
    __shared__ float pl[256];
    __shared__ float zs[128];
    const int gi = blockIdx.x;
    const int tid = threadIdx.x;

    float c = fmaxf(cnt[gi], 1.0f);
    float inv = 1.0f / c;
    for (int k = tid; k < 256; k += 128) pl[k] = sums[(size_t)gi * 256 + k] * inv;
    __syncthreads();

    float acc = b4[tid];
    for (int k = 0; k < 256; ++k) acc += pl[k] * w4t[k * 128 + tid];
    zs[tid] = fmaxf(acc, 0.0f);
    __syncthreads();

    if (tid < 64) {
        float v = zs[tid] * w5[tid] + zs[tid + 64] * w5[tid + 64];
#pragma unroll
        for (int off = 32; off > 0; off >>= 1) v += __shfl_down(v, off);
        if (tid == 0) out[gi] = 1.0f / (1.0f + expf(-(v + b5[0])));
    }
}

extern "C" void kernel_launch(void* const* d_in, const int* in_sizes, int n_in,
                              void* d_out, int out_size, void* d_ws, size_t ws_size,
                              hipStream_t stream)
{
    const float* x    = (const float*)d_in[0];
    const int*   ei   = (const int*)d_in[1];
    const float* ea   = (const float*)d_in[2];
    const int*   batch= (const int*)d_in[3];
    const float* we1  = (const float*)d_in[4];
    const float* be1  = (const float*)d_in[5];
    const float* wn1  = (const float*)d_in[6];
    const float* bnb1 = (const float*)d_in[7];
    const float* we2  = (const float*)d_in[8];
    const float* be2  = (const float*)d_in[9];
    const float* wn2  = (const float*)d_in[10];
    const float* bnb2 = (const float*)d_in[11];
    const float* we3  = (const float*)d_in[12];
    const float* be3  = (const float*)d_in[13];
    const float* wn3  = (const float*)d_in[14];
    const float* bnb3 = (const float*)d_in[15];
    const float* g1 = (const float*)d_in[16];
    const float* b1 = (const float*)d_in[17];
    const float* rm1= (const float*)d_in[18];
    const float* rv1= (const float*)d_in[19];
    const float* g2 = (const float*)d_in[20];
    const float* b2 = (const float*)d_in[21];
    const float* rm2= (const float*)d_in[22];
    const float* rv2= (const float*)d_in[23];
    const float* g3 = (const float*)d_in[24];
    const float* b3 = (const float*)d_in[25];
    const float* rm3= (const float*)d_in[26];
    const float* rv3= (const float*)d_in[27];
    const float* w4 = (const float*)d_in[28];
    const float* b4 = (const float*)d_in[29];
    const float* w5 = (const float*)d_in[30];
    const float* b5 = (const float*)d_in[31];

    const int N = in_sizes[0] / 64;
    const int E = in_sizes[1] / 2;
    const int G = out_size;

    float* ws   = (float*)d_ws;
    float* hbuf = ws;                                // N*256
    float* aggr = hbuf + (size_t)N * 256;            // N*256
    float* Wt   = aggr + (size_t)N * 256;            // 256*256
    float* w4t  = Wt + 256 * 256;                    // 256*128
    float* sums = w4t + 256 * 128;                   // G*256
    float* cnt  = sums + (size_t)G * 256;            // G

    const int nblk = (N + 31) / 32;

    // ---- Layer 1 (d_in = 64) ----
    k_copy<<<1024, 256, 0, stream>>>(x, aggr, N * 64 / 4);
    k_edge64<<<2048, 256, 0, stream>>>(ea, ei, E, x, we1, be1, aggr);
    k_transpose<<<(256 * 64 + 255) / 256, 256, 0, stream>>>(wn1, Wt, 256, 64);
    k_node<64><<<nblk, 256, 0, stream>>>(aggr, Wt, bnb1, g1, b1, rm1, rv1, hbuf, N);

    // ---- Layer 2 ----
    k_copy<<<2048, 256, 0, stream>>>(hbuf, aggr, N * 256 / 4);
    k_edge256<<<4096, 256, 0, stream>>>(ea, ei, E, hbuf, we2, be2, aggr);
    k_transpose<<<(256 * 256 + 255) / 256, 256, 0, stream>>>(wn2, Wt, 256, 256);
    k_node<256><<<nblk, 256, 0, stream>>>(aggr, Wt, bnb2, g2, b2, rm2, rv2, hbuf, N);

    // ---- Layer 3 ----
    k_copy<<<2048, 256, 0, stream>>>(hbuf, aggr, N * 256 / 4);
    k_edge256<<<4096, 256, 0, stream>>>(ea, ei, E, hbuf, we3, be3, aggr);
    k_transpose<<<(256 * 256 + 255) / 256, 256, 0, stream>>>(wn3, Wt, 256, 256);
    k_node<256><<<nblk, 256, 0, stream>>>(aggr, Wt, bnb3, g3, b3, rm3, rv3, hbuf, N);

    // ---- Pool + head ----
    k_zero<<<64, 256, 0, stream>>>(sums, (G * 256 + G) / 4);
    k_pool<<<2048, 256, 0, stream>>>(hbuf, batch, N, sums, cnt);
    k_transpose<<<(128 * 256 + 255) / 256, 256, 0, stream>>>(w4, w4t, 128, 256);
    k_head<<<G, 128, 0, stream>>>(sums, cnt, w4t, b4, w5, b5, (float*)d_out);
}

// Round 2
// 781.163 us; speedup vs baseline: 1.2135x; 1.2135x over previous
//
#include <hip/hip_runtime.h>
#include <hip/hip_bf16.h>
#include <math.h>

// ---------------------------------------------------------------------------
// GINE model: 3x (GINEConv + BN + ReLU) -> global mean pool -> MLP -> sigmoid
// Round 2: CSR gather (no scatter atomics), fused pool+head, float4-tiled GEMM.
// ---------------------------------------------------------------------------

__global__ void k_zero_i(int* __restrict__ p, int n) {
    int i = blockIdx.x * blockDim.x + threadIdx.x;
    int st = gridDim.x * blockDim.x;
    for (; i < n; i += st) p[i] = 0;
}

__global__ void k_copy_i(const int* __restrict__ s, int* __restrict__ d, int n) {
    int i = blockIdx.x * blockDim.x + threadIdx.x;
    int st = gridDim.x * blockDim.x;
    for (; i < n; i += st) d[i] = s[i];
}

// transpose W[J][K] -> Wt[K][J]
__global__ void k_transpose(const float* __restrict__ W, float* __restrict__ Wt, int J, int K) {
    int idx = blockIdx.x * blockDim.x + threadIdx.x;
    if (idx < J * K) {
        int j = idx / K, k = idx % K;
        Wt[k * J + j] = W[idx];
    }
}

// histogram of values v[i] in [0, nbins): cnt[v[i]]++
__global__ void k_hist(const int* __restrict__ v, int* __restrict__ cnt, int n) {
    int i = blockIdx.x * blockDim.x + threadIdx.x;
    int st = gridDim.x * blockDim.x;
    for (; i < n; i += st) atomicAdd(&cnt[v[i]], 1);
}

// single-block exclusive scan, out has n+1 entries (out[n] = total)
__global__ __launch_bounds__(1024) void k_scan(const int* __restrict__ in,
                                               int* __restrict__ out, int n) {
    __shared__ int wsum[16];
    __shared__ int carry_s;
    const int tid = threadIdx.x;
    const int lane = tid & 63, wv = tid >> 6;
    if (tid == 0) carry_s = 0;
    __syncthreads();
    for (int base = 0; base < n; base += 1024) {
        int idx = base + tid;
        int v = (idx < n) ? in[idx] : 0;
        int s = v;
#pragma unroll
        for (int off = 1; off < 64; off <<= 1) {
            int t = __shfl_up(s, off);
            if (lane >= off) s += t;
        }
        if (lane == 63) wsum[wv] = s;
        __syncthreads();
        int woff = 0;
        for (int i = 0; i < wv; ++i) woff += wsum[i];
        int carry = carry_s;
        if (idx < n) out[idx] = carry + woff + s - v;
        __syncthreads();
        if (tid == 1023) carry_s = carry + woff + s;
        __syncthreads();
    }
    if (tid == 0) out[n] = carry_s;
}

// bucket edges by dst: eid_s/esrc_s sorted by dst
__global__ void k_scatter(const int* __restrict__ ei, int E, int* __restrict__ cursor,
                          int* __restrict__ eid_s, int* __restrict__ esrc_s) {
    int i = blockIdx.x * blockDim.x + threadIdx.x;
    int st = gridDim.x * blockDim.x;
    for (; i < E; i += st) {
        int d = ei[E + i];
        int pos = atomicAdd(&cursor[d], 1);
        eid_s[pos] = i;
        esrc_s[pos] = ei[i];
    }
}

// Layer-1 gather (d=64): one wave per node; lane owns channel `lane`.
// aggr[n] = x[n] + sum_e relu(x[src] + ea@we.T + be)
__global__ __launch_bounds__(256) void k_gather64(
    const float* __restrict__ x, const int* __restrict__ rowptr,
    const int* __restrict__ eid_s, const int* __restrict__ esrc_s,
    const float* __restrict__ ea, const float* __restrict__ we,
    const float* __restrict__ be, float* __restrict__ aggr, int N)
{
    const int lane = threadIdx.x & 63;
    const int node = blockIdx.x * 4 + (threadIdx.x >> 6);
    float w[32];
    const float4* wr = (const float4*)(we + lane * 32);
#pragma unroll
    for (int q = 0; q < 8; ++q) {
        float4 t = wr[q];
        w[4*q] = t.x; w[4*q+1] = t.y; w[4*q+2] = t.z; w[4*q+3] = t.w;
    }
    const float bias = be[lane];
    if (node >= N) return;
    int beg = rowptr[node], end = rowptr[node + 1];
    float acc = x[(size_t)node * 64 + lane];
    for (int idx = beg; idx < end; ++idx) {
        int e = __builtin_amdgcn_readfirstlane(eid_s[idx]);
        int s = __builtin_amdgcn_readfirstlane(esrc_s[idx]);
        const float4* ea4 = (const float4*)(ea + (size_t)e * 32);
        float dot = bias;
#pragma unroll
        for (int q = 0; q < 8; ++q) {
            float4 t = ea4[q];
            dot += t.x * w[4*q] + t.y * w[4*q+1] + t.z * w[4*q+2] + t.w * w[4*q+3];
        }
        acc += fmaxf(x[(size_t)s * 64 + lane] + dot, 0.0f);
    }
    aggr[(size_t)node * 64 + lane] = acc;
}

// Layers 2/3 gather (d=256): one block (256 thr) per node; thread owns channel tid.
__global__ __launch_bounds__(256) void k_gather256(
    const float* __restrict__ h, const int* __restrict__ rowptr,
    const int* __restrict__ eid_s, const int* __restrict__ esrc_s,
    const float* __restrict__ ea, const float* __restrict__ we,
    const float* __restrict__ be, float* __restrict__ aggr, int N)
{
    const int n = blockIdx.x;
    const int c = threadIdx.x;
    float w[32];
    const float4* wr = (const float4*)(we + c * 32);
#pragma unroll
    for (int q = 0; q < 8; ++q) {
        float4 t = wr[q];
        w[4*q] = t.x; w[4*q+1] = t.y; w[4*q+2] = t.z; w[4*q+3] = t.w;
    }
    const float bias = be[c];
    int beg = rowptr[n], end = rowptr[n + 1];
    float acc = h[(size_t)n * 256 + c];
    for (int idx = beg; idx < end; ++idx) {
        int e = __builtin_amdgcn_readfirstlane(eid_s[idx]);
        int s = __builtin_amdgcn_readfirstlane(esrc_s[idx]);
        const float4* ea4 = (const float4*)(ea + (size_t)e * 32);
        float dot = bias;
#pragma unroll
        for (int q = 0; q < 8; ++q) {
            float4 t = ea4[q];
            dot += t.x * w[4*q] + t.y * w[4*q+1] + t.z * w[4*q+2] + t.w * w[4*q+3];
        }
        acc += fmaxf(h[(size_t)s * 256 + c] + dot, 0.0f);
    }
    aggr[(size_t)n * 256 + c] = acc;
}

// Node GEMM + BN + ReLU: out[N,256] = relu(BN(A[N,K] @ Wt[K,256] + bnb))
template<int K>
__global__ __launch_bounds__(256) void k_node(
    const float* __restrict__ A, const float* __restrict__ Wt,
    const float* __restrict__ bnb, const float* __restrict__ g,
    const float* __restrict__ b, const float* __restrict__ rm,
    const float* __restrict__ rv, float* __restrict__ out, int N)
{
    __shared__ float As[32 * K];
    const int tid = threadIdx.x;
    const int row0 = blockIdx.x * 32;
    const int nrows = min(32, N - row0);

    if (nrows == 32) {
        const float4* Ag = (const float4*)(A + (size_t)row0 * K);
        float4* As4 = (float4*)As;
        for (int i = tid; i < 32 * K / 4; i += 256) As4[i] = Ag[i];
    } else {
        for (int i = tid; i < nrows * K; i += 256) As[i] = A[(size_t)row0 * K + i];
    }
    __syncthreads();

    float acc[32];
#pragma unroll
    for (int i = 0; i < 32; ++i) acc[i] = 0.0f;

    for (int k = 0; k < K; k += 4) {
        float w0 = Wt[k * 256 + tid];
        float w1 = Wt[(k + 1) * 256 + tid];
        float w2 = Wt[(k + 2) * 256 + tid];
        float w3 = Wt[(k + 3) * 256 + tid];
#pragma unroll
        for (int i = 0; i < 32; ++i) {
            float4 a = *(const float4*)&As[i * K + k];
            acc[i] += a.x * w0 + a.y * w1 + a.z * w2 + a.w * w3;
        }
    }

    const float bias = bnb[tid];
    const float scale = g[tid] * rsqrtf(rv[tid] + 1e-5f);
    const float shift = b[tid] - rm[tid] * scale;
#pragma unroll
    for (int i = 0; i < 32; ++i) {
        if (i < nrows) {
            float v = (acc[i] + bias) * scale + shift;
            out[(size_t)(row0 + i) * 256 + tid] = fmaxf(v, 0.0f);
        }
    }
}

// Fused global-mean-pool + MLP head. One block per graph; batch is sorted so
// graph g owns node rows [gptr[g], gptr[g+1]).
__global__ __launch_bounds__(256) void k_pool_head(
    const float* __restrict__ h, const int* __restrict__ gptr,
    const float* __restrict__ w4t, const float* __restrict__ b4,
    const float* __restrict__ w5, const float* __restrict__ b5,
    float* __restrict__ out)
{
    __shared__ float pl[256];
    __shared__ float zs[128];
    const int g = blockIdx.x;
    const int tid = threadIdx.x;
    int beg = gptr[g], end = gptr[g + 1];
    float acc = 0.0f;
    for (int r = beg; r < end; ++r) acc += h[(size_t)r * 256 + tid];
    float cnt = (float)(end - beg);
    pl[tid] = acc / fmaxf(cnt, 1.0f);
    __syncthreads();
    if (tid < 128) {
        float a = b4[tid];
        for (int k = 0; k < 256; ++k) a += pl[k] * w4t[k * 128 + tid];
        zs[tid] = fmaxf(a, 0.0f);
    }
    __syncthreads();
    if (tid < 64) {
        float v = zs[tid] * w5[tid] + zs[tid + 64] * w5[tid + 64];
#pragma unroll
        for (int off = 32; off > 0; off >>= 1) v += __shfl_down(v, off);
        if (tid == 0) out[g] = 1.0f / (1.0f + expf(-(v + b5[0])));
    }
}

extern "C" void kernel_launch(void* const* d_in, const int* in_sizes, int n_in,
                              void* d_out, int out_size, void* d_ws, size_t ws_size,
                              hipStream_t stream)
{
    const float* x    = (const float*)d_in[0];
    const int*   ei   = (const int*)d_in[1];
    const float* ea   = (const float*)d_in[2];
    const int*   batch= (const int*)d_in[3];
    const float* we1  = (const float*)d_in[4];
    const float* be1  = (const float*)d_in[5];
    const float* wn1  = (const float*)d_in[6];
    const float* bnb1 = (const float*)d_in[7];
    const float* we2  = (const float*)d_in[8];
    const float* be2  = (const float*)d_in[9];
    const float* wn2  = (const float*)d_in[10];
    const float* bnb2 = (const float*)d_in[11];
    const float* we3  = (const float*)d_in[12];
    const float* be3  = (const float*)d_in[13];
    const float* wn3  = (const float*)d_in[14];
    const float* bnb3 = (const float*)d_in[15];
    const float* g1 = (const float*)d_in[16];
    const float* b1 = (const float*)d_in[17];
    const float* rm1= (const float*)d_in[18];
    const float* rv1= (const float*)d_in[19];
    const float* g2 = (const float*)d_in[20];
    const float* b2 = (const float*)d_in[21];
    const float* rm2= (const float*)d_in[22];
    const float* rv2= (const float*)d_in[23];
    const float* g3 = (const float*)d_in[24];
    const float* b3 = (const float*)d_in[25];
    const float* rm3= (const float*)d_in[26];
    const float* rv3= (const float*)d_in[27];
    const float* w4 = (const float*)d_in[28];
    const float* b4 = (const float*)d_in[29];
    const float* w5 = (const float*)d_in[30];
    const float* b5 = (const float*)d_in[31];

    const int N = in_sizes[0] / 64;
    const int E = in_sizes[1] / 2;
    const int G = out_size;

    // float workspace
    float* ws   = (float*)d_ws;
    float* hbuf = ws;                                // N*256
    float* aggr = hbuf + (size_t)N * 256;            // N*256
    float* Wt   = aggr + (size_t)N * 256;            // 256*256
    float* w4t  = Wt + 256 * 256;                    // 256*128
    // int workspace
    int* iws    = (int*)(w4t + 256 * 128);
    int* ideg   = iws;                               // N
    int* rowptr = ideg + N;                          // N+1
    int* cursor = rowptr + N + 1;                    // N
    int* eid_s  = cursor + N;                        // E
    int* esrc_s = eid_s + E;                         // E
    int* gcnt   = esrc_s + E;                        // G
    int* gptr   = gcnt + G;                          // G+1

    const int nblk = (N + 31) / 32;

    // ---- CSR build + graph ranges ----
    k_zero_i<<<64, 256, 0, stream>>>(ideg, N);
    k_zero_i<<<4, 256, 0, stream>>>(gcnt, G);
    k_hist<<<512, 256, 0, stream>>>(ei + E, ideg, E);   // dst histogram
    k_hist<<<128, 256, 0, stream>>>(batch, gcnt, N);
    k_scan<<<1, 1024, 0, stream>>>(ideg, rowptr, N);
    k_scan<<<1, 1024, 0, stream>>>(gcnt, gptr, G);
    k_copy_i<<<64, 256, 0, stream>>>(rowptr, cursor, N);
    k_scatter<<<512, 256, 0, stream>>>(ei, E, cursor, eid_s, esrc_s);

    // ---- Layer 1 (d_in = 64) ----
    k_gather64<<<(N + 3) / 4, 256, 0, stream>>>(x, rowptr, eid_s, esrc_s, ea, we1, be1, aggr, N);
    k_transpose<<<(256 * 64 + 255) / 256, 256, 0, stream>>>(wn1, Wt, 256, 64);
    k_node<64><<<nblk, 256, 0, stream>>>(aggr, Wt, bnb1, g1, b1, rm1, rv1, hbuf, N);

    // ---- Layer 2 ----
    k_gather256<<<N, 256, 0, stream>>>(hbuf, rowptr, eid_s, esrc_s, ea, we2, be2, aggr, N);
    k_transpose<<<(256 * 256 + 255) / 256, 256, 0, stream>>>(wn2, Wt, 256, 256);
    k_node<256><<<nblk, 256, 0, stream>>>(aggr, Wt, bnb2, g2, b2, rm2, rv2, hbuf, N);

    // ---- Layer 3 ----
    k_gather256<<<N, 256, 0, stream>>>(hbuf, rowptr, eid_s, esrc_s, ea, we3, be3, aggr, N);
    k_transpose<<<(256 * 256 + 255) / 256, 256, 0, stream>>>(wn3, Wt, 256, 256);
    k_node<256><<<nblk, 256, 0, stream>>>(aggr, Wt, bnb3, g3, b3, rm3, rv3, hbuf, N);

    // ---- Fused pool + head ----
    k_transpose<<<(128 * 256 + 255) / 256, 256, 0, stream>>>(w4, w4t, 128, 256);
    k_pool_head<<<G, 256, 0, stream>>>(hbuf, gptr, w4t, b4, w5, b5, (float*)d_out);
}